// Round 1
// baseline (155238.953 us; speedup 1.0000x reference)
//
#include <hip/hip_runtime.h>
#include <math.h>

#define N_DST   25000
#define DN      128
#define DE      128
#define DTF     100
#define DKV     356   // 128 + 128 + 100
#define DQ      228   // 128 + 100
#define DOUT    128
#define LEAKY   0.2f
#define LN_EPS  1e-5f

// ---- workspace layout (bytes) ----
#define OFF_V       0ull                    // E * 128 f32       = 204,800,000
#define OFF_SCORE   204800000ull            // E * 2 f32         =   3,200,000
#define OFF_QN      208000000ull            // 25000 * 128 f32   =  12,800,000
#define OFF_CNT     220800000ull            // 25000 i32
#define OFF_OFFS    220900000ull            // 25001 i32
#define OFF_CURSOR  221000004ull            // 25000 i32
#define OFF_ELIST   221100004ull            // E i32
// total ~222.7 MB

// ---------------------------------------------------------------------------
// q_nodes[r][j] = bq[j] + sum_k h[r][k]*Wq[j][k] + sum_t cos(b_t[t])*Wq[j][128+t]
// ---------------------------------------------------------------------------
__global__ __launch_bounds__(128) void k_qnodes(const float* __restrict__ h,
                                                const float* __restrict__ Wq,
                                                const float* __restrict__ bq,
                                                const float* __restrict__ b_t,
                                                float* __restrict__ qn) {
    __shared__ float wq_s[128 * 132];   // row j padded to 132 floats
    __shared__ float hrow[128];
    const int j = threadIdx.x;          // 0..127 output col

    #pragma unroll
    for (int k4 = 0; k4 < 128; k4 += 4) {
        float4 w = *(const float4*)&Wq[j * DQ + k4];
        *(float4*)&wq_s[j * 132 + k4] = w;
    }
    float cq = bq[j];
    for (int k = 0; k < DTF; ++k)
        cq += Wq[j * DQ + 128 + k] * cosf(b_t[k]);
    __syncthreads();

    for (int r = blockIdx.x; r < N_DST; r += gridDim.x) {
        if (j < 32)
            *(float4*)&hrow[j * 4] = *(const float4*)&h[(size_t)r * DN + j * 4];
        __syncthreads();
        float acc = cq;
        #pragma unroll
        for (int k = 0; k < 128; k += 4) {
            float4 hv = *(float4*)&hrow[k];
            float4 wv = *(float4*)&wq_s[j * 132 + k];
            acc += hv.x * wv.x + hv.y * wv.y + hv.z * wv.z + hv.w * wv.w;
        }
        qn[(size_t)r * DOUT + j] = acc;
        __syncthreads();
    }
}

// ---------------------------------------------------------------------------
// CSR build
// ---------------------------------------------------------------------------
__global__ void k_hist(const int* __restrict__ dst, int* __restrict__ cnt, int E) {
    int i = blockIdx.x * 256 + threadIdx.x;
    if (i < E) atomicAdd(&cnt[dst[i]], 1);
}

__global__ __launch_bounds__(256) void k_scan(const int* __restrict__ cnt,
                                              int* __restrict__ offs,
                                              int* __restrict__ cursor) {
    __shared__ int totals[256];
    __shared__ int bases[257];
    const int t = threadIdx.x;
    const int STRIP = (N_DST + 255) / 256;   // 98
    int s = 0;
    for (int i = 0; i < STRIP; ++i) {
        int idx = t * STRIP + i;
        if (idx < N_DST) s += cnt[idx];
    }
    totals[t] = s;
    __syncthreads();
    if (t == 0) {
        int run = 0;
        for (int i = 0; i < 256; ++i) { bases[i] = run; run += totals[i]; }
        bases[256] = run;
    }
    __syncthreads();
    int run = bases[t];
    for (int i = 0; i < STRIP; ++i) {
        int idx = t * STRIP + i;
        if (idx < N_DST) {
            offs[idx] = run;
            cursor[idx] = run;
            run += cnt[idx];
        }
    }
    if (t == 0) offs[N_DST] = bases[256];
}

__global__ void k_scatter(const int* __restrict__ dst, int* __restrict__ cursor,
                          int* __restrict__ elist, int E) {
    int i = blockIdx.x * 256 + threadIdx.x;
    if (i < E) {
        int d = dst[i];
        int pos = atomicAdd(&cursor[d], 1);
        elist[pos] = i;
    }
}

// ---------------------------------------------------------------------------
// Per-edge K,V projection + attention score.  32 edges / block, 256 threads.
// kv_in = [h[src] | f | cos(dt*w_t+b_t)]  (356)
// K = kv_in @ Wk.T + bk ; V = kv_in @ Wv.T + bv
// score[e][hd] = leaky_relu( dot(Q[e][hd*64: ], K[e][hd*64: ]) )
// ---------------------------------------------------------------------------
__global__ __launch_bounds__(256) void k_edge(const float* __restrict__ h,
                                              const float* __restrict__ f,
                                              const float* __restrict__ dtv,
                                              const int* __restrict__ src_idx,
                                              const int* __restrict__ dst_idx,
                                              const float* __restrict__ w_t,
                                              const float* __restrict__ b_t,
                                              const float* __restrict__ Wk,
                                              const float* __restrict__ bk,
                                              const float* __restrict__ Wv,
                                              const float* __restrict__ bv,
                                              const float* __restrict__ qn,
                                              float* __restrict__ Vout,
                                              float* __restrict__ score,
                                              int E) {
    __shared__ float At[DKV][32];     // kv_in transposed: [k][edge]
    __shared__ float Bt[32][256];     // W chunk transposed: [k][col], col<128=K,>=128=V
    __shared__ int   sidx[32];
    __shared__ int   didx[32];

    const int tid   = threadIdx.x;
    const int eBase = blockIdx.x * 32;

    if (tid < 32) {
        int ge = eBase + tid;
        sidx[tid] = (ge < E) ? src_idx[ge] : 0;
        didx[tid] = (ge < E) ? dst_idx[ge] : 0;
    }
    __syncthreads();

    // stage A (gather + time encoding): 32 edges x 89 float4 quads
    for (int u = tid; u < 32 * 89; u += 256) {
        int e = u / 89, q = u - e * 89, c = q * 4;
        int ge = eBase + e;
        float4 v = make_float4(0.f, 0.f, 0.f, 0.f);
        if (ge < E) {
            if (c < 128) {
                v = *(const float4*)&h[(size_t)sidx[e] * DN + c];
            } else if (c < 256) {
                v = *(const float4*)&f[(size_t)ge * DE + (c - 128)];
            } else {
                int t0 = c - 256;
                float d = dtv[ge];
                v.x = cosf(d * w_t[t0 + 0] + b_t[t0 + 0]);
                v.y = cosf(d * w_t[t0 + 1] + b_t[t0 + 1]);
                v.z = cosf(d * w_t[t0 + 2] + b_t[t0 + 2]);
                v.w = cosf(d * w_t[t0 + 3] + b_t[t0 + 3]);
            }
        }
        At[c + 0][e] = v.x;
        At[c + 1][e] = v.y;
        At[c + 2][e] = v.z;
        At[c + 3][e] = v.w;
    }
    __syncthreads();

    const int tcol = tid & 31;   // col group: cols tcol*4..+3 (K) and 128+tcol*4..+3 (V)
    const int trow = tid >> 5;   // edge group: edges trow*4..+3

    float accK[4][4], accV[4][4];
    {
        float4 bk4 = *(const float4*)&bk[tcol * 4];
        float4 bv4 = *(const float4*)&bv[tcol * 4];
        #pragma unroll
        for (int e = 0; e < 4; ++e) {
            accK[e][0] = bk4.x; accK[e][1] = bk4.y; accK[e][2] = bk4.z; accK[e][3] = bk4.w;
            accV[e][0] = bv4.x; accV[e][1] = bv4.y; accV[e][2] = bv4.z; accV[e][3] = bv4.w;
        }
    }

    for (int kc = 0; kc < DKV; kc += 32) {
        const int klen = min(32, DKV - kc);
        // stage B chunk: thread tid owns output col tid
        {
            const float* wrow = (tid < 128) ? &Wk[(size_t)tid * DKV]
                                            : &Wv[(size_t)(tid - 128) * DKV];
            for (int kk = 0; kk < klen; kk += 4) {
                float4 w = *(const float4*)&wrow[kc + kk];
                Bt[kk + 0][tid] = w.x;
                Bt[kk + 1][tid] = w.y;
                Bt[kk + 2][tid] = w.z;
                Bt[kk + 3][tid] = w.w;
            }
        }
        __syncthreads();
        for (int kk = 0; kk < klen; ++kk) {
            float4 a   = *(float4*)&At[kc + kk][trow * 4];
            float4 bK  = *(float4*)&Bt[kk][tcol * 4];
            float4 bV  = *(float4*)&Bt[kk][128 + tcol * 4];
            float av[4] = {a.x, a.y, a.z, a.w};
            #pragma unroll
            for (int e = 0; e < 4; ++e) {
                accK[e][0] += av[e] * bK.x;
                accK[e][1] += av[e] * bK.y;
                accK[e][2] += av[e] * bK.z;
                accK[e][3] += av[e] * bK.w;
                accV[e][0] += av[e] * bV.x;
                accV[e][1] += av[e] * bV.y;
                accV[e][2] += av[e] * bV.z;
                accV[e][3] += av[e] * bV.w;
            }
        }
        __syncthreads();
    }

    // scores: Q[e][tcol*4..+3] . K partial, reduce across 16 lanes (one head half)
    #pragma unroll
    for (int e = 0; e < 4; ++e) {
        int le = trow * 4 + e;
        int ge = eBase + le;
        int d  = didx[le];
        float4 q = *(const float4*)&qn[(size_t)d * DOUT + tcol * 4];
        float p = q.x * accK[e][0] + q.y * accK[e][1] + q.z * accK[e][2] + q.w * accK[e][3];
        p += __shfl_xor(p, 1);
        p += __shfl_xor(p, 2);
        p += __shfl_xor(p, 4);
        p += __shfl_xor(p, 8);
        if ((tcol & 15) == 0 && ge < E) {
            int hd = tcol >> 4;
            float s = (p >= 0.f) ? p : LEAKY * p;
            score[(size_t)ge * 2 + hd] = s;
        }
    }

    // V out, coalesced float4
    #pragma unroll
    for (int e = 0; e < 4; ++e) {
        int ge = eBase + trow * 4 + e;
        if (ge < E) {
            float4 v4 = make_float4(accV[e][0], accV[e][1], accV[e][2], accV[e][3]);
            *(float4*)&Vout[(size_t)ge * DOUT + tcol * 4] = v4;
        }
    }
}

// ---------------------------------------------------------------------------
// Per-dst: softmax over incoming edges, weighted V sum, output proj + ReLU + LN
// ---------------------------------------------------------------------------
__global__ __launch_bounds__(128) void k_dst(const float* __restrict__ V,
                                             const float* __restrict__ score,
                                             const int* __restrict__ offs,
                                             const int* __restrict__ elist,
                                             const float* __restrict__ h,
                                             const float* __restrict__ Wout,
                                             const float* __restrict__ bout,
                                             const float* __restrict__ ln_w,
                                             const float* __restrict__ ln_b,
                                             float* __restrict__ out) {
    const int d = blockIdx.x;
    const int j = threadIdx.x;   // 0..127
    const int beg = offs[d], end = offs[d + 1];

    __shared__ float red[4];
    __shared__ float inc[256];

    // pass A: per-head max
    float m0 = -1e30f, m1 = -1e30f;
    for (int i = beg + j; i < end; i += 128) {
        int e = elist[i];
        m0 = fmaxf(m0, score[(size_t)e * 2 + 0]);
        m1 = fmaxf(m1, score[(size_t)e * 2 + 1]);
    }
    #pragma unroll
    for (int o = 1; o < 64; o <<= 1) {
        m0 = fmaxf(m0, __shfl_xor(m0, o));
        m1 = fmaxf(m1, __shfl_xor(m1, o));
    }
    if ((j & 63) == 0) { red[j >> 6] = m0; red[2 + (j >> 6)] = m1; }
    __syncthreads();
    m0 = fmaxf(red[0], red[1]);
    m1 = fmaxf(red[2], red[3]);

    // pass B: exp-weighted V accumulation
    const int   hd = j >> 6;
    const float mh = hd ? m1 : m0;
    float acc = 0.f, l = 0.f;
    for (int i = beg; i < end; ++i) {
        int e = elist[i];
        float w = __expf(score[(size_t)e * 2 + hd] - mh);
        l += w;
        acc += w * V[(size_t)e * DOUT + j];
    }
    float agg = (l > 0.f) ? (acc / l) : 0.f;

    __syncthreads();            // red reuse below, barrier before inc writes anyway
    inc[j]       = agg;
    inc[128 + j] = h[(size_t)d * DN + j];
    __syncthreads();

    // rst[j] = relu(bout[j] + Wout[j] . inc)
    float r = bout[j];
    #pragma unroll 8
    for (int k = 0; k < 256; k += 4) {
        float4 w4 = *(const float4*)&Wout[(size_t)j * 256 + k];
        r += w4.x * inc[k] + w4.y * inc[k + 1] + w4.z * inc[k + 2] + w4.w * inc[k + 3];
    }
    r = fmaxf(r, 0.f);

    // LayerNorm over 128 cols
    float s1 = r, s2 = r * r;
    #pragma unroll
    for (int o = 1; o < 64; o <<= 1) {
        s1 += __shfl_xor(s1, o);
        s2 += __shfl_xor(s2, o);
    }
    __syncthreads();
    if ((j & 63) == 0) { red[j >> 6] = s1; red[2 + (j >> 6)] = s2; }
    __syncthreads();
    s1 = red[0] + red[1];
    s2 = red[2] + red[3];
    float mu  = s1 * (1.f / 128.f);
    float var = s2 * (1.f / 128.f) - mu * mu;
    float xn  = (r - mu) * rsqrtf(var + LN_EPS);
    out[(size_t)d * DOUT + j] = xn * ln_w[j] + ln_b[j];
}

// ---------------------------------------------------------------------------
extern "C" void kernel_launch(void* const* d_in, const int* in_sizes, int n_in,
                              void* d_out, int out_size, void* d_ws, size_t ws_size,
                              hipStream_t stream) {
    const float* h       = (const float*)d_in[0];
    const float* f       = (const float*)d_in[1];
    const float* dt      = (const float*)d_in[2];
    const int*   src_idx = (const int*)d_in[3];
    const int*   dst_idx = (const int*)d_in[4];
    const float* w_t     = (const float*)d_in[5];
    const float* b_t     = (const float*)d_in[6];
    const float* Wq      = (const float*)d_in[7];
    const float* bq      = (const float*)d_in[8];
    const float* Wk      = (const float*)d_in[9];
    const float* bk      = (const float*)d_in[10];
    const float* Wv      = (const float*)d_in[11];
    const float* bv      = (const float*)d_in[12];
    const float* Wout    = (const float*)d_in[13];
    const float* bout    = (const float*)d_in[14];
    const float* ln_w    = (const float*)d_in[15];
    const float* ln_b    = (const float*)d_in[16];
    float*       out     = (float*)d_out;

    const int E = in_sizes[2];          // dt element count = #edges

    char* ws = (char*)d_ws;
    float* V      = (float*)(ws + OFF_V);
    float* score  = (float*)(ws + OFF_SCORE);
    float* qn     = (float*)(ws + OFF_QN);
    int*   cnt    = (int*)(ws + OFF_CNT);
    int*   offs   = (int*)(ws + OFF_OFFS);
    int*   cursor = (int*)(ws + OFF_CURSOR);
    int*   elist  = (int*)(ws + OFF_ELIST);

    hipMemsetAsync(cnt, 0, N_DST * sizeof(int), stream);

    k_qnodes<<<512, 128, 0, stream>>>(h, Wq, bq, b_t, qn);
    k_hist<<<(E + 255) / 256, 256, 0, stream>>>(dst_idx, cnt, E);
    k_scan<<<1, 256, 0, stream>>>(cnt, offs, cursor);
    k_scatter<<<(E + 255) / 256, 256, 0, stream>>>(dst_idx, cursor, elist, E);
    k_edge<<<(E + 31) / 32, 256, 0, stream>>>(h, f, dt, src_idx, dst_idx, w_t, b_t,
                                              Wk, bk, Wv, bv, qn, V, score, E);
    k_dst<<<N_DST, 128, 0, stream>>>(V, score, offs, elist, h, Wout, bout,
                                     ln_w, ln_b, out);
}

// Round 2
// 1400.815 us; speedup vs baseline: 110.8204x; 110.8204x over previous
//
#include <hip/hip_runtime.h>
#include <math.h>

#define N_DST   25000
#define DN      128
#define DE      128
#define DTF     100
#define DKV     356   // 128 + 128 + 100
#define KP      384   // DKV zero-padded to multiple of 32
#define DQ      228
#define DOUT    128
#define LEAKY   0.2f
#define LN_EPS  1e-5f
#define LDA     392   // LDS stride for A tile (bf16 elems), padded vs 384

// ---- workspace layout (bytes) ----
#define OFF_V       0ull            // E*128 bf16      = 102,400,000
#define OFF_SCORE   102400000ull    // E*2 f32         =   3,200,000
#define OFF_QN      105600000ull    // 25000*128 f32   =  12,800,000
#define OFF_WB      118400000ull    // 256*384 bf16    =     196,608
#define OFF_CNT     118600000ull    // 25000 i32
#define OFF_OFFS    118700000ull    // 25001 i32
#define OFF_CURSOR  118800004ull    // 25000 i32
#define OFF_ELIST   118900004ull    // E i32
// total ~120.5 MB  (round-1 layout used 222.7 MB, so ws_size is sufficient)

typedef __attribute__((ext_vector_type(8))) short short8;
typedef __attribute__((ext_vector_type(4))) float f32x4;

__device__ __forceinline__ unsigned short f2bf(float x) {
    union { float f; unsigned u; } v; v.f = x;
    unsigned r = v.u + 0x7FFFu + ((v.u >> 16) & 1u);
    return (unsigned short)(r >> 16);
}
__device__ __forceinline__ float bf2f(unsigned short u) {
    union { unsigned u; float f; } v; v.u = ((unsigned)u) << 16;
    return v.f;
}

// ---------------------------------------------------------------------------
// WB[n][k] (bf16, row-major, stride KP): n<128 -> Wk[n], n>=128 -> Wv[n-128];
// k >= DKV zero-padded. This is exactly the B^T layout the MFMA B-frag wants.
// ---------------------------------------------------------------------------
__global__ __launch_bounds__(128) void k_prepw(const float* __restrict__ Wk,
                                               const float* __restrict__ Wv,
                                               unsigned short* __restrict__ WB) {
    const int n = blockIdx.x;       // 0..255
    const float* src = (n < 128) ? &Wk[(size_t)n * DKV] : &Wv[(size_t)(n - 128) * DKV];
    for (int k = threadIdx.x; k < KP; k += 128) {
        float v = (k < DKV) ? src[k] : 0.f;
        WB[(size_t)n * KP + k] = f2bf(v);
    }
}

// ---------------------------------------------------------------------------
// q_nodes (fp32, small: 0.8 GFLOP)
// ---------------------------------------------------------------------------
__global__ __launch_bounds__(128) void k_qnodes(const float* __restrict__ h,
                                                const float* __restrict__ Wq,
                                                const float* __restrict__ bq,
                                                const float* __restrict__ b_t,
                                                float* __restrict__ qn) {
    __shared__ float wq_s[128 * 132];
    __shared__ float hrow[128];
    const int j = threadIdx.x;

    for (int k4 = 0; k4 < 128; k4 += 4) {
        float4 w = *(const float4*)&Wq[j * DQ + k4];
        *(float4*)&wq_s[j * 132 + k4] = w;
    }
    float cq = bq[j];
    for (int k = 0; k < DTF; ++k)
        cq += Wq[j * DQ + 128 + k] * cosf(b_t[k]);
    __syncthreads();

    for (int r = blockIdx.x; r < N_DST; r += gridDim.x) {
        if (j < 32)
            *(float4*)&hrow[j * 4] = *(const float4*)&h[(size_t)r * DN + j * 4];
        __syncthreads();
        float acc = cq;
        for (int k = 0; k < 128; k += 4) {
            float4 hv = *(float4*)&hrow[k];
            float4 wv = *(float4*)&wq_s[j * 132 + k];
            acc += hv.x * wv.x + hv.y * wv.y + hv.z * wv.z + hv.w * wv.w;
        }
        qn[(size_t)r * DOUT + j] = acc;
        __syncthreads();
    }
}

// ---------------------------------------------------------------------------
// CSR build
// ---------------------------------------------------------------------------
__global__ void k_hist(const int* __restrict__ dst, int* __restrict__ cnt, int E) {
    int i = blockIdx.x * 256 + threadIdx.x;
    if (i < E) atomicAdd(&cnt[dst[i]], 1);
}

__global__ __launch_bounds__(256) void k_scan(const int* __restrict__ cnt,
                                              int* __restrict__ offs,
                                              int* __restrict__ cursor) {
    __shared__ int totals[256];
    __shared__ int bases[257];
    const int t = threadIdx.x;
    const int STRIP = (N_DST + 255) / 256;
    int s = 0;
    for (int i = 0; i < STRIP; ++i) {
        int idx = t * STRIP + i;
        if (idx < N_DST) s += cnt[idx];
    }
    totals[t] = s;
    __syncthreads();
    if (t == 0) {
        int run = 0;
        for (int i = 0; i < 256; ++i) { bases[i] = run; run += totals[i]; }
        bases[256] = run;
    }
    __syncthreads();
    int run = bases[t];
    for (int i = 0; i < STRIP; ++i) {
        int idx = t * STRIP + i;
        if (idx < N_DST) {
            offs[idx] = run;
            cursor[idx] = run;
            run += cnt[idx];
        }
    }
    if (t == 0) offs[N_DST] = bases[256];
}

__global__ void k_scatter(const int* __restrict__ dst, int* __restrict__ cursor,
                          int* __restrict__ elist, int E) {
    int i = blockIdx.x * 256 + threadIdx.x;
    if (i < E) {
        int d = dst[i];
        int pos = atomicAdd(&cursor[d], 1);
        elist[pos] = i;
    }
}

// ---------------------------------------------------------------------------
// Edge K/V projection via bf16 MFMA + attention scores.
// Block: 64 edges x 256 out-cols, 4 waves. Wave w owns cols [w*64, w*64+64):
// 4x4 tiles of mfma_f32_16x16x32_bf16, 12 K-chunks (KP=384).
// A (gathered kv_in -> bf16) staged in LDS; B frags read from WB (L2-resident).
// Waves 0,1 own K cols (head 0,1): compute leaky_relu(Q.K) scores in-register.
// Waves 2,3 own V cols: store V as bf16.
// ---------------------------------------------------------------------------
__global__ __launch_bounds__(256) void k_edge(const float* __restrict__ h,
                                              const float* __restrict__ f,
                                              const float* __restrict__ dtv,
                                              const int* __restrict__ src_idx,
                                              const int* __restrict__ dst_idx,
                                              const float* __restrict__ w_t,
                                              const float* __restrict__ b_t,
                                              const unsigned short* __restrict__ WB,
                                              const float* __restrict__ bk,
                                              const float* __restrict__ bv,
                                              const float* __restrict__ qn,
                                              unsigned short* __restrict__ Vout,
                                              float* __restrict__ score,
                                              int E) {
    __shared__ unsigned short At[64 * LDA];
    __shared__ int sidx[64];
    __shared__ int didx[64];

    const int tid = threadIdx.x;
    const int e0  = blockIdx.x * 64;

    if (tid < 64) {
        int ge = e0 + tid;
        sidx[tid] = (ge < E) ? src_idx[ge] : 0;
        didx[tid] = (ge < E) ? dst_idx[ge] : 0;
    }
    __syncthreads();

    // ---- stage A: 64 edges x 96 quads (fp32 gather -> bf16 LDS) ----
    {
        const int e  = tid >> 2;          // 0..63
        const int ge = e0 + e;
        const int qb = tid & 3;
        const int s  = sidx[e];
        const float dte = (ge < E) ? dtv[ge] : 0.f;
        #pragma unroll 1
        for (int it = 0; it < 24; ++it) {
            const int c = (qb + it * 4) * 4;   // 0,16,..,380 interleaved
            float4 v = make_float4(0.f, 0.f, 0.f, 0.f);
            if (ge < E) {
                if (c < 128) {
                    v = *(const float4*)&h[(size_t)s * DN + c];
                } else if (c < 256) {
                    v = *(const float4*)&f[(size_t)ge * DE + (c - 128)];
                } else if (c < 356) {
                    int t0 = c - 256;
                    v.x = cosf(dte * w_t[t0 + 0] + b_t[t0 + 0]);
                    v.y = cosf(dte * w_t[t0 + 1] + b_t[t0 + 1]);
                    v.z = cosf(dte * w_t[t0 + 2] + b_t[t0 + 2]);
                    v.w = cosf(dte * w_t[t0 + 3] + b_t[t0 + 3]);
                }
            }
            union { unsigned short us[4]; uint2 u2; } pk;
            pk.us[0] = f2bf(v.x); pk.us[1] = f2bf(v.y);
            pk.us[2] = f2bf(v.z); pk.us[3] = f2bf(v.w);
            *(uint2*)&At[e * LDA + c] = pk.u2;
        }
    }
    __syncthreads();

    // ---- MFMA main loop ----
    const int lane = tid & 63;
    const int w    = tid >> 6;     // wave = col group
    const int t16  = lane & 15;
    const int qd   = lane >> 4;    // 0..3

    f32x4 acc[4][4];
    #pragma unroll
    for (int r = 0; r < 4; ++r)
        #pragma unroll
        for (int c = 0; c < 4; ++c)
            acc[r][c] = (f32x4){0.f, 0.f, 0.f, 0.f};

    const unsigned short* bbase = WB + ((size_t)(w * 64 + t16) * KP + qd * 8);

    #pragma unroll 1
    for (int kc = 0; kc < 12; ++kc) {
        short8 af[4], bfr[4];
        #pragma unroll
        for (int r = 0; r < 4; ++r)
            af[r] = *(const short8*)&At[(r * 16 + t16) * LDA + kc * 32 + qd * 8];
        #pragma unroll
        for (int c = 0; c < 4; ++c)
            bfr[c] = *(const short8*)(bbase + (size_t)c * 16 * KP + kc * 32);
        #pragma unroll
        for (int r = 0; r < 4; ++r)
            #pragma unroll
            for (int c = 0; c < 4; ++c)
                acc[r][c] = __builtin_amdgcn_mfma_f32_16x16x32_bf16(af[r], bfr[c], acc[r][c], 0, 0, 0);
    }

    // ---- epilogue ----
    // C/D layout: col = lane&15 (out col within 16-tile), row = qd*4 + reg (edge)
    if (w >= 2) {
        const int vc0 = (w - 2) * 64;
        #pragma unroll
        for (int c = 0; c < 4; ++c) {
            const int vcol = vc0 + c * 16 + t16;
            const float bvv = bv[vcol];
            #pragma unroll
            for (int r = 0; r < 4; ++r) {
                #pragma unroll
                for (int i = 0; i < 4; ++i) {
                    int ge = e0 + r * 16 + qd * 4 + i;
                    if (ge < E)
                        Vout[(size_t)ge * DOUT + vcol] = f2bf(acc[r][c][i] + bvv);
                }
            }
        }
    } else {
        float bkc[4];
        #pragma unroll
        for (int c = 0; c < 4; ++c)
            bkc[c] = bk[w * 64 + c * 16 + t16];
        #pragma unroll
        for (int r = 0; r < 4; ++r) {
            #pragma unroll
            for (int i = 0; i < 4; ++i) {
                const int el = r * 16 + qd * 4 + i;
                const int d  = didx[el];
                const float* qrow = &qn[(size_t)d * DOUT + w * 64 + t16];
                float p = (acc[r][0][i] + bkc[0]) * qrow[0]
                        + (acc[r][1][i] + bkc[1]) * qrow[16]
                        + (acc[r][2][i] + bkc[2]) * qrow[32]
                        + (acc[r][3][i] + bkc[3]) * qrow[48];
                p += __shfl_xor(p, 1);
                p += __shfl_xor(p, 2);
                p += __shfl_xor(p, 4);
                p += __shfl_xor(p, 8);
                if (t16 == 0) {
                    int ge = e0 + el;
                    if (ge < E) {
                        float sc = (p >= 0.f) ? p : LEAKY * p;
                        score[(size_t)ge * 2 + w] = sc;
                    }
                }
            }
        }
    }
}

// ---------------------------------------------------------------------------
// Per-dst softmax + weighted V sum + out-proj + ReLU + LayerNorm.
// 4 dsts per block (512 threads) to amortize Wout L2 reads.
// ---------------------------------------------------------------------------
__global__ __launch_bounds__(512) void k_dst(const unsigned short* __restrict__ V,
                                             const float* __restrict__ score,
                                             const int* __restrict__ offs,
                                             const int* __restrict__ elist,
                                             const float* __restrict__ h,
                                             const float* __restrict__ Wout,
                                             const float* __restrict__ bout,
                                             const float* __restrict__ ln_w,
                                             const float* __restrict__ ln_b,
                                             float* __restrict__ out) {
    const int sub = threadIdx.x >> 7;        // 0..3
    const int j   = threadIdx.x & 127;       // 0..127
    const int d   = blockIdx.x * 4 + sub;    // N_DST = 4*6250 exact
    const int beg = offs[d], end = offs[d + 1];

    __shared__ float sm[4][2][2];
    __shared__ float inc[4][256];

    // pass A: per-head max
    float m0 = -1e30f, m1 = -1e30f;
    for (int i = beg + j; i < end; i += 128) {
        int e = elist[i];
        m0 = fmaxf(m0, score[(size_t)e * 2 + 0]);
        m1 = fmaxf(m1, score[(size_t)e * 2 + 1]);
    }
    #pragma unroll
    for (int o = 1; o < 64; o <<= 1) {
        m0 = fmaxf(m0, __shfl_xor(m0, o));
        m1 = fmaxf(m1, __shfl_xor(m1, o));
    }
    if ((j & 63) == 0) { sm[sub][j >> 6][0] = m0; sm[sub][j >> 6][1] = m1; }
    __syncthreads();
    m0 = fmaxf(sm[sub][0][0], sm[sub][1][0]);
    m1 = fmaxf(sm[sub][0][1], sm[sub][1][1]);

    // pass B: exp-weighted V accumulation
    const int   hd = j >> 6;
    const float mh = hd ? m1 : m0;
    float acc = 0.f, l = 0.f;
    for (int i = beg; i < end; ++i) {
        int e = elist[i];
        float wgt = __expf(score[(size_t)e * 2 + hd] - mh);
        l += wgt;
        acc += wgt * bf2f(V[(size_t)e * DOUT + j]);
    }
    float agg = (l > 0.f) ? (acc / l) : 0.f;

    inc[sub][j]       = agg;
    inc[sub][128 + j] = h[(size_t)d * DN + j];
    __syncthreads();

    // rst[j] = relu(bout[j] + Wout[j] . [agg | h_d])
    float r = bout[j];
    #pragma unroll 8
    for (int k = 0; k < 256; k += 4) {
        float4 w4 = *(const float4*)&Wout[(size_t)j * 256 + k];
        r += w4.x * inc[sub][k] + w4.y * inc[sub][k + 1]
           + w4.z * inc[sub][k + 2] + w4.w * inc[sub][k + 3];
    }
    r = fmaxf(r, 0.f);

    // LayerNorm over 128 cols
    float s1 = r, s2 = r * r;
    #pragma unroll
    for (int o = 1; o < 64; o <<= 1) {
        s1 += __shfl_xor(s1, o);
        s2 += __shfl_xor(s2, o);
    }
    __syncthreads();   // sm reuse
    if ((j & 63) == 0) { sm[sub][j >> 6][0] = s1; sm[sub][j >> 6][1] = s2; }
    __syncthreads();
    s1 = sm[sub][0][0] + sm[sub][1][0];
    s2 = sm[sub][0][1] + sm[sub][1][1];
    float mu  = s1 * (1.f / 128.f);
    float var = s2 * (1.f / 128.f) - mu * mu;
    float xn  = (r - mu) * rsqrtf(var + LN_EPS);
    out[(size_t)d * DOUT + j] = xn * ln_w[j] + ln_b[j];
}

// ---------------------------------------------------------------------------
extern "C" void kernel_launch(void* const* d_in, const int* in_sizes, int n_in,
                              void* d_out, int out_size, void* d_ws, size_t ws_size,
                              hipStream_t stream) {
    const float* h       = (const float*)d_in[0];
    const float* f       = (const float*)d_in[1];
    const float* dt      = (const float*)d_in[2];
    const int*   src_idx = (const int*)d_in[3];
    const int*   dst_idx = (const int*)d_in[4];
    const float* w_t     = (const float*)d_in[5];
    const float* b_t     = (const float*)d_in[6];
    const float* Wq      = (const float*)d_in[7];
    const float* bq      = (const float*)d_in[8];
    const float* Wk      = (const float*)d_in[9];
    const float* bk      = (const float*)d_in[10];
    const float* Wv      = (const float*)d_in[11];
    const float* bv      = (const float*)d_in[12];
    const float* Wout    = (const float*)d_in[13];
    const float* bout    = (const float*)d_in[14];
    const float* ln_w    = (const float*)d_in[15];
    const float* ln_b    = (const float*)d_in[16];
    float*       out     = (float*)d_out;

    const int E = in_sizes[2];

    char* ws = (char*)d_ws;
    unsigned short* V  = (unsigned short*)(ws + OFF_V);
    float* score       = (float*)(ws + OFF_SCORE);
    float* qn          = (float*)(ws + OFF_QN);
    unsigned short* WB = (unsigned short*)(ws + OFF_WB);
    int*   cnt         = (int*)(ws + OFF_CNT);
    int*   offs        = (int*)(ws + OFF_OFFS);
    int*   cursor      = (int*)(ws + OFF_CURSOR);
    int*   elist       = (int*)(ws + OFF_ELIST);

    hipMemsetAsync(cnt, 0, N_DST * sizeof(int), stream);

    k_prepw<<<256, 128, 0, stream>>>(Wk, Wv, WB);
    k_qnodes<<<512, 128, 0, stream>>>(h, Wq, bq, b_t, qn);
    k_hist<<<(E + 255) / 256, 256, 0, stream>>>(dst_idx, cnt, E);
    k_scan<<<1, 256, 0, stream>>>(cnt, offs, cursor);
    k_scatter<<<(E + 255) / 256, 256, 0, stream>>>(dst_idx, cursor, elist, E);
    k_edge<<<(E + 63) / 64, 256, 0, stream>>>(h, f, dt, src_idx, dst_idx, w_t, b_t,
                                              WB, bk, bv, qn, V, score, E);
    k_dst<<<N_DST / 4, 512, 0, stream>>>(V, score, offs, elist, h, Wout, bout,
                                         ln_w, ln_b, out);
}

// Round 3
// 875.315 us; speedup vs baseline: 177.3522x; 1.6004x over previous
//
#include <hip/hip_runtime.h>
#include <math.h>

#define N_DST   25000
#define DN      128
#define DE      128
#define DTF     100
#define DKV     356   // 128 + 128 + 100
#define KP      384   // DKV zero-padded to multiple of 32
#define DQ      228
#define DOUT    128
#define LEAKY   0.2f
#define LN_EPS  1e-5f
#define LDA     392   // LDS stride for A tile (bf16 elems)

// ---- workspace layout (bytes) ----
#define OFF_V       0ull            // E*128 bf16 (CSR order) = 102,400,000
#define OFF_SCORE   102400000ull    // E*2 f32   (CSR order) =   3,200,000
#define OFF_QN      105600000ull    // 25000*128 f32          =  12,800,000
#define OFF_WS      118400000ull    // swizzled Wk|Wv bf16    =     196,608
#define OFF_WT      118700000ull    // WoutT f32 256x128      =     131,072
#define OFF_CNT     118900000ull    // 25000 i32
#define OFF_OFFS    119000000ull    // 25001 i32
#define OFF_CURSOR  119100004ull    // 25000 i32
#define OFF_RANK    119200004ull    // E i32
// total ~120.8 MB

typedef __attribute__((ext_vector_type(8))) short short8;
typedef __attribute__((ext_vector_type(4))) float f32x4;

__device__ __forceinline__ unsigned short f2bf(float x) {
    union { float f; unsigned u; } v; v.f = x;
    unsigned r = v.u + 0x7FFFu + ((v.u >> 16) & 1u);
    return (unsigned short)(r >> 16);
}
__device__ __forceinline__ float bf2f(unsigned short u) {
    union { unsigned u; float f; } v; v.u = ((unsigned)u) << 16;
    return v.f;
}

// ---------------------------------------------------------------------------
// WS: swizzled bf16 weight table so a wave's B-frag load is contiguous 1 KB.
// For (n, k): kc=k/32, qd=(k%32)/8, j=k%8, c16=n/16, t16=n%16
//   WS[ ((kc*16 + c16)*64 + qd*16 + t16)*8 + j ]
// Lane l (t16=l&15, qd=l>>4) of col-tile c16, chunk kc loads 16 B at
//   byte ofs (kc*16+c16)*1024 + l*16  -> wave = contiguous 1024 B.
// ---------------------------------------------------------------------------
__global__ __launch_bounds__(128) void k_prepw(const float* __restrict__ Wk,
                                               const float* __restrict__ Wv,
                                               unsigned short* __restrict__ WS) {
    const int n = blockIdx.x;       // 0..255
    const float* src = (n < 128) ? &Wk[(size_t)n * DKV] : &Wv[(size_t)(n - 128) * DKV];
    const int c16 = n >> 4, t16 = n & 15;
    for (int k = threadIdx.x; k < KP; k += 128) {
        float v = (k < DKV) ? src[k] : 0.f;
        int kc = k >> 5, qd = (k >> 3) & 3, j = k & 7;
        WS[(size_t)(((kc * 16 + c16) * 64 + qd * 16 + t16) * 8 + j)] = f2bf(v);
    }
}

__global__ __launch_bounds__(128) void k_prepwt(const float* __restrict__ Wout,
                                                float* __restrict__ WT) {
    const int k = blockIdx.x;       // 0..255
    const int j = threadIdx.x;      // 0..127
    WT[k * 128 + j] = Wout[(size_t)j * 256 + k];
}

// ---------------------------------------------------------------------------
// q_nodes (fp32), 8 rows per round for ILP
// ---------------------------------------------------------------------------
__global__ __launch_bounds__(128) void k_qnodes(const float* __restrict__ h,
                                                const float* __restrict__ Wq,
                                                const float* __restrict__ bq,
                                                const float* __restrict__ b_t,
                                                float* __restrict__ qn) {
    __shared__ float wq_s[128 * 132];
    __shared__ float hrow[8 * 128];
    const int j = threadIdx.x;

    for (int k4 = 0; k4 < 128; k4 += 4) {
        float4 w = *(const float4*)&Wq[j * DQ + k4];
        *(float4*)&wq_s[j * 132 + k4] = w;
    }
    float cq = bq[j];
    for (int k = 0; k < DTF; ++k)
        cq += Wq[j * DQ + 128 + k] * cosf(b_t[k]);
    __syncthreads();

    for (int r0 = blockIdx.x * 8; r0 < N_DST; r0 += gridDim.x * 8) {
        for (int u = j; u < 256; u += 128) {
            int rr = u >> 5, q = u & 31;
            int r = r0 + rr;
            float4 v = make_float4(0.f, 0.f, 0.f, 0.f);
            if (r < N_DST) v = *(const float4*)&h[(size_t)r * DN + q * 4];
            *(float4*)&hrow[rr * 128 + q * 4] = v;
        }
        __syncthreads();
        float acc[8];
        #pragma unroll
        for (int rr = 0; rr < 8; ++rr) acc[rr] = cq;
        for (int k4 = 0; k4 < 128; k4 += 4) {
            float4 wv = *(float4*)&wq_s[j * 132 + k4];
            #pragma unroll
            for (int rr = 0; rr < 8; ++rr) {
                float4 hv = *(float4*)&hrow[rr * 128 + k4];
                acc[rr] += hv.x * wv.x + hv.y * wv.y + hv.z * wv.z + hv.w * wv.w;
            }
        }
        #pragma unroll
        for (int rr = 0; rr < 8; ++rr)
            if (r0 + rr < N_DST) qn[(size_t)(r0 + rr) * DOUT + j] = acc[rr];
        __syncthreads();
    }
}

// ---------------------------------------------------------------------------
// CSR build (+ rank = per-edge CSR position)
// ---------------------------------------------------------------------------
__global__ void k_hist(const int* __restrict__ dst, int* __restrict__ cnt, int E) {
    int i = blockIdx.x * 256 + threadIdx.x;
    if (i < E) atomicAdd(&cnt[dst[i]], 1);
}

__global__ __launch_bounds__(256) void k_scan(const int* __restrict__ cnt,
                                              int* __restrict__ offs,
                                              int* __restrict__ cursor) {
    __shared__ int totals[256];
    __shared__ int bases[257];
    const int t = threadIdx.x;
    const int STRIP = (N_DST + 255) / 256;
    int s = 0;
    for (int i = 0; i < STRIP; ++i) {
        int idx = t * STRIP + i;
        if (idx < N_DST) s += cnt[idx];
    }
    totals[t] = s;
    __syncthreads();
    if (t == 0) {
        int run = 0;
        for (int i = 0; i < 256; ++i) { bases[i] = run; run += totals[i]; }
        bases[256] = run;
    }
    __syncthreads();
    int run = bases[t];
    for (int i = 0; i < STRIP; ++i) {
        int idx = t * STRIP + i;
        if (idx < N_DST) {
            offs[idx] = run;
            cursor[idx] = run;
            run += cnt[idx];
        }
    }
    if (t == 0) offs[N_DST] = bases[256];
}

__global__ void k_scatter(const int* __restrict__ dst, int* __restrict__ cursor,
                          int* __restrict__ rank, int E) {
    int i = blockIdx.x * 256 + threadIdx.x;
    if (i < E) {
        int d = dst[i];
        int pos = atomicAdd(&cursor[d], 1);
        rank[i] = pos;
    }
}

// ---------------------------------------------------------------------------
// Edge K/V projection via bf16 MFMA + attention scores, CSR-ordered outputs.
// ---------------------------------------------------------------------------
__global__ __launch_bounds__(256, 3) void k_edge(const float* __restrict__ h,
                                                 const float* __restrict__ f,
                                                 const float* __restrict__ dtv,
                                                 const int* __restrict__ src_idx,
                                                 const int* __restrict__ dst_idx,
                                                 const int* __restrict__ rank,
                                                 const float* __restrict__ w_t,
                                                 const float* __restrict__ b_t,
                                                 const unsigned short* __restrict__ WS,
                                                 const float* __restrict__ bk,
                                                 const float* __restrict__ bv,
                                                 const float* __restrict__ qn,
                                                 unsigned short* __restrict__ Vout,
                                                 float* __restrict__ score,
                                                 int E) {
    __shared__ unsigned short At[64 * LDA];
    __shared__ int sidx[64];
    __shared__ int didx[64];
    __shared__ int rks[64];

    const int tid = threadIdx.x;
    const int e0  = blockIdx.x * 64;

    if (tid < 64) {
        int ge = min(e0 + tid, E - 1);
        sidx[tid] = src_idx[ge];
        didx[tid] = dst_idx[ge];
        rks[tid]  = rank[ge];
    }
    __syncthreads();

    // ---- stage A: batched 8-deep loads, fp32 -> bf16 LDS ----
    {
        const int e  = tid >> 2;          // 0..63
        const int qb = tid & 3;
        const int ge = min(e0 + e, E - 1);
        const int s  = sidx[e];
        const float dte = dtv[ge];
        const float* hb = &h[(size_t)s * DN];
        const float* fb = &f[(size_t)ge * DE];
        float4 buf[8];

        #pragma unroll
        for (int it = 0; it < 8; ++it) buf[it] = *(const float4*)&hb[qb * 4 + it * 16];
        #pragma unroll
        for (int it = 0; it < 8; ++it) {
            int c = qb * 4 + it * 16;
            union { unsigned short us[4]; uint2 u2; } pk;
            pk.us[0] = f2bf(buf[it].x); pk.us[1] = f2bf(buf[it].y);
            pk.us[2] = f2bf(buf[it].z); pk.us[3] = f2bf(buf[it].w);
            *(uint2*)&At[e * LDA + c] = pk.u2;
        }
        #pragma unroll
        for (int it = 0; it < 8; ++it) buf[it] = *(const float4*)&fb[qb * 4 + it * 16];
        #pragma unroll
        for (int it = 0; it < 8; ++it) {
            int c = 128 + qb * 4 + it * 16;
            union { unsigned short us[4]; uint2 u2; } pk;
            pk.us[0] = f2bf(buf[it].x); pk.us[1] = f2bf(buf[it].y);
            pk.us[2] = f2bf(buf[it].z); pk.us[3] = f2bf(buf[it].w);
            *(uint2*)&At[e * LDA + c] = pk.u2;
        }
        #pragma unroll
        for (int it = 0; it < 8; ++it) {
            int t0 = qb * 4 + it * 16;         // 0..124, multiple of 4
            float4 v = make_float4(0.f, 0.f, 0.f, 0.f);
            if (t0 < DTF) {
                v.x = cosf(dte * w_t[t0 + 0] + b_t[t0 + 0]);
                v.y = cosf(dte * w_t[t0 + 1] + b_t[t0 + 1]);
                v.z = cosf(dte * w_t[t0 + 2] + b_t[t0 + 2]);
                v.w = cosf(dte * w_t[t0 + 3] + b_t[t0 + 3]);
            }
            union { unsigned short us[4]; uint2 u2; } pk;
            pk.us[0] = f2bf(v.x); pk.us[1] = f2bf(v.y);
            pk.us[2] = f2bf(v.z); pk.us[3] = f2bf(v.w);
            *(uint2*)&At[e * LDA + 256 + t0] = pk.u2;
        }
    }
    __syncthreads();

    // ---- MFMA main loop, A/B register double-buffered ----
    const int lane = tid & 63;
    const int w    = tid >> 6;
    const int t16  = lane & 15;
    const int qd   = lane >> 4;
    const int w4   = w * 4;

    f32x4 acc[4][4];
    #pragma unroll
    for (int r = 0; r < 4; ++r)
        #pragma unroll
        for (int c = 0; c < 4; ++c)
            acc[r][c] = (f32x4){0.f, 0.f, 0.f, 0.f};

    short8 aC[4], aN[4], bC[4], bN[4];
    #pragma unroll
    for (int r = 0; r < 4; ++r)
        aC[r] = *(const short8*)&At[(r * 16 + t16) * LDA + qd * 8];
    #pragma unroll
    for (int c = 0; c < 4; ++c)
        bC[c] = *(const short8*)(WS + (size_t)((0 * 16 + w4 + c) * 64 + lane) * 8);

    #pragma unroll 1
    for (int kc = 0; kc < 12; kc += 2) {
        #pragma unroll
        for (int r = 0; r < 4; ++r)
            aN[r] = *(const short8*)&At[(r * 16 + t16) * LDA + (kc + 1) * 32 + qd * 8];
        #pragma unroll
        for (int c = 0; c < 4; ++c)
            bN[c] = *(const short8*)(WS + (size_t)(((kc + 1) * 16 + w4 + c) * 64 + lane) * 8);
        #pragma unroll
        for (int r = 0; r < 4; ++r)
            #pragma unroll
            for (int c = 0; c < 4; ++c)
                acc[r][c] = __builtin_amdgcn_mfma_f32_16x16x32_bf16(aC[r], bC[c], acc[r][c], 0, 0, 0);
        if (kc + 2 < 12) {
            #pragma unroll
            for (int r = 0; r < 4; ++r)
                aC[r] = *(const short8*)&At[(r * 16 + t16) * LDA + (kc + 2) * 32 + qd * 8];
            #pragma unroll
            for (int c = 0; c < 4; ++c)
                bC[c] = *(const short8*)(WS + (size_t)(((kc + 2) * 16 + w4 + c) * 64 + lane) * 8);
        }
        #pragma unroll
        for (int r = 0; r < 4; ++r)
            #pragma unroll
            for (int c = 0; c < 4; ++c)
                acc[r][c] = __builtin_amdgcn_mfma_f32_16x16x32_bf16(aN[r], bN[c], acc[r][c], 0, 0, 0);
    }

    // ---- epilogue (C/D: outcol = c*16+t16, edge = r*16 + qd*4 + i) ----
    if (w >= 2) {
        const int vc0 = (w - 2) * 64;
        #pragma unroll
        for (int c = 0; c < 4; ++c) {
            const int vcol = vc0 + c * 16 + t16;
            const float bvv = bv[vcol];
            #pragma unroll
            for (int r = 0; r < 4; ++r) {
                #pragma unroll
                for (int i = 0; i < 4; ++i) {
                    int el = r * 16 + qd * 4 + i;
                    int ge = e0 + el;
                    if (ge < E)
                        Vout[(size_t)rks[el] * DOUT + vcol] = f2bf(acc[r][c][i] + bvv);
                }
            }
        }
    } else {
        float bkc[4];
        #pragma unroll
        for (int c = 0; c < 4; ++c)
            bkc[c] = bk[w * 64 + c * 16 + t16];
        #pragma unroll
        for (int r = 0; r < 4; ++r) {
            #pragma unroll
            for (int i = 0; i < 4; ++i) {
                const int el = r * 16 + qd * 4 + i;
                const int d  = didx[el];
                const float* qrow = &qn[(size_t)d * DOUT + w * 64 + t16];
                float p = (acc[r][0][i] + bkc[0]) * qrow[0]
                        + (acc[r][1][i] + bkc[1]) * qrow[16]
                        + (acc[r][2][i] + bkc[2]) * qrow[32]
                        + (acc[r][3][i] + bkc[3]) * qrow[48];
                p += __shfl_xor(p, 1);
                p += __shfl_xor(p, 2);
                p += __shfl_xor(p, 4);
                p += __shfl_xor(p, 8);
                if (t16 == 0) {
                    int ge = e0 + el;
                    if (ge < E) {
                        float sc = (p >= 0.f) ? p : LEAKY * p;
                        score[(size_t)rks[el] * 2 + w] = sc;
                    }
                }
            }
        }
    }
}

// ---------------------------------------------------------------------------
// Per-dst: softmax + weighted V sum (CSR streams) + out-proj + ReLU + LN.
// 512 threads = 16 dsts x 32 threads (4 cols each). WoutT staged via LDS.
// ---------------------------------------------------------------------------
__global__ __launch_bounds__(512) void k_dst(const unsigned short* __restrict__ V,
                                             const float* __restrict__ score,
                                             const int* __restrict__ offs,
                                             const float* __restrict__ h,
                                             const float* __restrict__ WT,
                                             const float* __restrict__ bout,
                                             const float* __restrict__ ln_w,
                                             const float* __restrict__ ln_b,
                                             float* __restrict__ out) {
    const int tid = threadIdx.x;
    const int s   = tid >> 5;        // sub 0..15
    const int t32 = tid & 31;
    const int d   = blockIdx.x * 16 + s;
    const bool valid = d < N_DST;
    const int beg = valid ? offs[d] : 0;
    const int end = valid ? offs[d + 1] : 0;

    __shared__ float inc[16][256];
    __shared__ float wchunk[64 * 128];

    // pass A: per-head max (contiguous CSR scores)
    float m0 = -1e30f, m1 = -1e30f;
    for (int i = beg + t32; i < end; i += 32) {
        float2 sc = *(const float2*)&score[(size_t)i * 2];
        m0 = fmaxf(m0, sc.x);
        m1 = fmaxf(m1, sc.y);
    }
    #pragma unroll
    for (int o = 1; o < 32; o <<= 1) {
        m0 = fmaxf(m0, __shfl_xor(m0, o));
        m1 = fmaxf(m1, __shfl_xor(m1, o));
    }
    const int   hd = t32 >> 4;
    const float mh = hd ? m1 : m0;

    // pass B: exp-weighted V accumulation (contiguous rows)
    float a0 = 0.f, a1 = 0.f, a2 = 0.f, a3 = 0.f, l = 0.f;
    int i = beg;
    for (; i + 1 < end; i += 2) {
        float s0 = score[(size_t)i * 2 + hd];
        float s1 = score[(size_t)(i + 1) * 2 + hd];
        ushort4 v0 = *(const ushort4*)&V[(size_t)i * DOUT + t32 * 4];
        ushort4 v1 = *(const ushort4*)&V[(size_t)(i + 1) * DOUT + t32 * 4];
        float w0 = __expf(s0 - mh);
        float w1 = __expf(s1 - mh);
        l += w0 + w1;
        a0 += w0 * bf2f(v0.x) + w1 * bf2f(v1.x);
        a1 += w0 * bf2f(v0.y) + w1 * bf2f(v1.y);
        a2 += w0 * bf2f(v0.z) + w1 * bf2f(v1.z);
        a3 += w0 * bf2f(v0.w) + w1 * bf2f(v1.w);
    }
    if (i < end) {
        float s0 = score[(size_t)i * 2 + hd];
        ushort4 v0 = *(const ushort4*)&V[(size_t)i * DOUT + t32 * 4];
        float w0 = __expf(s0 - mh);
        l += w0;
        a0 += w0 * bf2f(v0.x);
        a1 += w0 * bf2f(v0.y);
        a2 += w0 * bf2f(v0.z);
        a3 += w0 * bf2f(v0.w);
    }
    float inv = (l > 0.f) ? (1.f / l) : 0.f;
    inc[s][t32 * 4 + 0] = a0 * inv;
    inc[s][t32 * 4 + 1] = a1 * inv;
    inc[s][t32 * 4 + 2] = a2 * inv;
    inc[s][t32 * 4 + 3] = a3 * inv;
    {
        float4 hh = make_float4(0.f, 0.f, 0.f, 0.f);
        if (valid) hh = *(const float4*)&h[(size_t)d * DN + t32 * 4];
        *(float4*)&inc[s][128 + t32 * 4] = hh;
    }

    // out-proj: r4 = bout + WoutT . inc, staged in 4 x 32KB LDS chunks
    float4 r4 = *(const float4*)&bout[t32 * 4];
    #pragma unroll 1
    for (int ch = 0; ch < 4; ++ch) {
        __syncthreads();
        for (int u = tid; u < 2048; u += 512)
            *(float4*)&wchunk[u * 4] = *(const float4*)&WT[(size_t)ch * 8192 + u * 4];
        __syncthreads();
        #pragma unroll 4
        for (int kk = 0; kk < 64; ++kk) {
            float ic = inc[s][ch * 64 + kk];
            float4 w4 = *(float4*)&wchunk[kk * 128 + t32 * 4];
            r4.x += w4.x * ic;
            r4.y += w4.y * ic;
            r4.z += w4.z * ic;
            r4.w += w4.w * ic;
        }
    }
    r4.x = fmaxf(r4.x, 0.f);
    r4.y = fmaxf(r4.y, 0.f);
    r4.z = fmaxf(r4.z, 0.f);
    r4.w = fmaxf(r4.w, 0.f);

    // LayerNorm over the dst's 128 cols (32 lanes x 4)
    float s1 = r4.x + r4.y + r4.z + r4.w;
    float s2 = r4.x * r4.x + r4.y * r4.y + r4.z * r4.z + r4.w * r4.w;
    #pragma unroll
    for (int o = 1; o < 32; o <<= 1) {
        s1 += __shfl_xor(s1, o);
        s2 += __shfl_xor(s2, o);
    }
    float mu  = s1 * (1.f / 128.f);
    float var = s2 * (1.f / 128.f) - mu * mu;
    float rsd = rsqrtf(var + LN_EPS);
    if (valid) {
        float4 lw = *(const float4*)&ln_w[t32 * 4];
        float4 lb = *(const float4*)&ln_b[t32 * 4];
        float4 o4;
        o4.x = (r4.x - mu) * rsd * lw.x + lb.x;
        o4.y = (r4.y - mu) * rsd * lw.y + lb.y;
        o4.z = (r4.z - mu) * rsd * lw.z + lb.z;
        o4.w = (r4.w - mu) * rsd * lw.w + lb.w;
        *(float4*)&out[(size_t)d * DOUT + t32 * 4] = o4;
    }
}

// ---------------------------------------------------------------------------
extern "C" void kernel_launch(void* const* d_in, const int* in_sizes, int n_in,
                              void* d_out, int out_size, void* d_ws, size_t ws_size,
                              hipStream_t stream) {
    const float* h       = (const float*)d_in[0];
    const float* f       = (const float*)d_in[1];
    const float* dt      = (const float*)d_in[2];
    const int*   src_idx = (const int*)d_in[3];
    const int*   dst_idx = (const int*)d_in[4];
    const float* w_t     = (const float*)d_in[5];
    const float* b_t     = (const float*)d_in[6];
    const float* Wq      = (const float*)d_in[7];
    const float* bq      = (const float*)d_in[8];
    const float* Wk      = (const float*)d_in[9];
    const float* bk      = (const float*)d_in[10];
    const float* Wv      = (const float*)d_in[11];
    const float* bv      = (const float*)d_in[12];
    const float* Wout    = (const float*)d_in[13];
    const float* bout    = (const float*)d_in[14];
    const float* ln_w    = (const float*)d_in[15];
    const float* ln_b    = (const float*)d_in[16];
    float*       out     = (float*)d_out;

    const int E = in_sizes[2];

    char* ws = (char*)d_ws;
    unsigned short* V  = (unsigned short*)(ws + OFF_V);
    float* score       = (float*)(ws + OFF_SCORE);
    float* qn          = (float*)(ws + OFF_QN);
    unsigned short* WS = (unsigned short*)(ws + OFF_WS);
    float* WT          = (float*)(ws + OFF_WT);
    int*   cnt         = (int*)(ws + OFF_CNT);
    int*   offs        = (int*)(ws + OFF_OFFS);
    int*   cursor      = (int*)(ws + OFF_CURSOR);
    int*   rank        = (int*)(ws + OFF_RANK);

    hipMemsetAsync(cnt, 0, N_DST * sizeof(int), stream);

    k_prepw<<<256, 128, 0, stream>>>(Wk, Wv, WS);
    k_prepwt<<<256, 128, 0, stream>>>(Wout, WT);
    k_qnodes<<<512, 128, 0, stream>>>(h, Wq, bq, b_t, qn);
    k_hist<<<(E + 255) / 256, 256, 0, stream>>>(dst_idx, cnt, E);
    k_scan<<<1, 256, 0, stream>>>(cnt, offs, cursor);
    k_scatter<<<(E + 255) / 256, 256, 0, stream>>>(dst_idx, cursor, rank, E);
    k_edge<<<(E + 63) / 64, 256, 0, stream>>>(h, f, dt, src_idx, dst_idx, rank,
                                              w_t, b_t, WS, bk, bv, qn, V, score, E);
    k_dst<<<(N_DST + 15) / 16, 512, 0, stream>>>(V, score, offs, h, WT, bout,
                                                 ln_w, ln_b, out);
}

// Round 4
// 799.038 us; speedup vs baseline: 194.2823x; 1.0955x over previous
//
#include <hip/hip_runtime.h>
#include <math.h>

#define N_DST   25000
#define DN      128
#define DE      128
#define DTF     100
#define DKV     356   // 128 + 128 + 100
#define KP      384   // DKV zero-padded to multiple of 32
#define DQ      228
#define DOUT    128
#define LEAKY   0.2f
#define LN_EPS  1e-5f
#define LDA     392   // LDS stride for A tile (bf16 elems)
#define INV2PI  0.15915494309189535f

// ---- workspace layout (bytes) ----
#define OFF_V       0ull            // E*128 bf16 (edge order) = 102,400,000
#define OFF_SCORE   102400000ull    // E*2 f32   (edge order)  =   3,200,000
#define OFF_QN      105600000ull    // 25000*128 f32           =  12,800,000
#define OFF_WS      118400000ull    // swizzled Wk|Wv bf16     =     196,608
#define OFF_WT      118700000ull    // WoutT f32 256x128       =     131,072
#define OFF_CNT     118900000ull    // 25000 i32
#define OFF_OFFS    119000000ull    // 25001 i32
#define OFF_CURSOR  119100004ull    // 25000 i32
#define OFF_ELIST   119200004ull    // E i32
// total ~120.8 MB

typedef __attribute__((ext_vector_type(8))) short short8;
typedef __attribute__((ext_vector_type(4))) float f32x4;

__device__ __forceinline__ unsigned short f2bf(float x) {
    union { float f; unsigned u; } v; v.f = x;
    unsigned r = v.u + 0x7FFFu + ((v.u >> 16) & 1u);
    return (unsigned short)(r >> 16);
}
__device__ __forceinline__ float bf2f(unsigned short u) {
    union { unsigned u; float f; } v; v.u = ((unsigned)u) << 16;
    return v.f;
}
// fast cos: phase error <= ~1e-4 revolutions at |x|<=1e4 — far below bf16 rounding
__device__ __forceinline__ float fastcos(float x) {
    return __builtin_amdgcn_cosf(__builtin_amdgcn_fractf(x * INV2PI));
}

// ---------------------------------------------------------------------------
// WS: swizzled bf16 weight table so a wave's B-frag load is contiguous 1 KB.
// ---------------------------------------------------------------------------
__global__ __launch_bounds__(128) void k_prepw(const float* __restrict__ Wk,
                                               const float* __restrict__ Wv,
                                               unsigned short* __restrict__ WS) {
    const int n = blockIdx.x;       // 0..255
    const float* src = (n < 128) ? &Wk[(size_t)n * DKV] : &Wv[(size_t)(n - 128) * DKV];
    const int c16 = n >> 4, t16 = n & 15;
    for (int k = threadIdx.x; k < KP; k += 128) {
        float v = (k < DKV) ? src[k] : 0.f;
        int kc = k >> 5, qd = (k >> 3) & 3, j = k & 7;
        WS[(size_t)(((kc * 16 + c16) * 64 + qd * 16 + t16) * 8 + j)] = f2bf(v);
    }
}

__global__ __launch_bounds__(128) void k_prepwt(const float* __restrict__ Wout,
                                                float* __restrict__ WT) {
    const int k = blockIdx.x;       // 0..255
    const int j = threadIdx.x;      // 0..127
    WT[k * 128 + j] = Wout[(size_t)j * 256 + k];
}

// ---------------------------------------------------------------------------
// q_nodes fp32: 256 thr = (col j, k-half kh). Wq half-row in regs, 16 rows/blk.
// ---------------------------------------------------------------------------
__global__ __launch_bounds__(256) void k_qnodes(const float* __restrict__ h,
                                                const float* __restrict__ Wq,
                                                const float* __restrict__ bq,
                                                const float* __restrict__ b_t,
                                                float* __restrict__ qn) {
    __shared__ float hrows[16 * 128];
    __shared__ float part[16 * 128];
    const int tid = threadIdx.x;
    const int j  = tid & 127;
    const int kh = tid >> 7;

    float wq[64];
    #pragma unroll
    for (int k = 0; k < 64; k += 4) {
        float4 w = *(const float4*)&Wq[j * DQ + kh * 64 + k];
        wq[k] = w.x; wq[k + 1] = w.y; wq[k + 2] = w.z; wq[k + 3] = w.w;
    }
    float cq = 0.f;
    if (kh == 0) {
        cq = bq[j];
        for (int k = 0; k < DTF; ++k)
            cq += Wq[j * DQ + 128 + k] * fastcos(b_t[k]);
    }

    const int r0 = blockIdx.x * 16;
    for (int u = tid; u < 512; u += 256) {          // 512 float4s = 16 rows
        int rr = u >> 5, q = u & 31;
        int r = r0 + rr;
        float4 v = make_float4(0.f, 0.f, 0.f, 0.f);
        if (r < N_DST) v = *(const float4*)&h[(size_t)r * DN + q * 4];
        *(float4*)&hrows[rr * 128 + q * 4] = v;
    }
    __syncthreads();

    float acc[16];
    #pragma unroll
    for (int rr = 0; rr < 16; ++rr) acc[rr] = 0.f;
    #pragma unroll
    for (int k4 = 0; k4 < 64; k4 += 4) {
        float w0 = wq[k4], w1 = wq[k4 + 1], w2 = wq[k4 + 2], w3 = wq[k4 + 3];
        #pragma unroll
        for (int rr = 0; rr < 16; ++rr) {
            float4 hv = *(float4*)&hrows[rr * 128 + kh * 64 + k4];
            acc[rr] += w0 * hv.x + w1 * hv.y + w2 * hv.z + w3 * hv.w;
        }
    }
    if (kh == 1) {
        #pragma unroll
        for (int rr = 0; rr < 16; ++rr) part[rr * 128 + j] = acc[rr];
    }
    __syncthreads();
    if (kh == 0) {
        #pragma unroll
        for (int rr = 0; rr < 16; ++rr) {
            int r = r0 + rr;
            if (r < N_DST)
                qn[(size_t)r * DOUT + j] = acc[rr] + part[rr * 128 + j] + cq;
        }
    }
}

// ---------------------------------------------------------------------------
// CSR build (elist = edge ids in CSR order)
// ---------------------------------------------------------------------------
__global__ void k_hist(const int* __restrict__ dst, int* __restrict__ cnt, int E) {
    int i = blockIdx.x * 256 + threadIdx.x;
    if (i < E) atomicAdd(&cnt[dst[i]], 1);
}

__global__ __launch_bounds__(256) void k_scan(const int* __restrict__ cnt,
                                              int* __restrict__ offs,
                                              int* __restrict__ cursor) {
    __shared__ int totals[256];
    __shared__ int bases[257];
    const int t = threadIdx.x;
    const int STRIP = (N_DST + 255) / 256;
    int s = 0;
    for (int i = 0; i < STRIP; ++i) {
        int idx = t * STRIP + i;
        if (idx < N_DST) s += cnt[idx];
    }
    totals[t] = s;
    __syncthreads();
    if (t == 0) {
        int run = 0;
        for (int i = 0; i < 256; ++i) { bases[i] = run; run += totals[i]; }
        bases[256] = run;
    }
    __syncthreads();
    int run = bases[t];
    for (int i = 0; i < STRIP; ++i) {
        int idx = t * STRIP + i;
        if (idx < N_DST) {
            offs[idx] = run;
            cursor[idx] = run;
            run += cnt[idx];
        }
    }
    if (t == 0) offs[N_DST] = bases[256];
}

__global__ void k_scatter(const int* __restrict__ dst, int* __restrict__ cursor,
                          int* __restrict__ elist, int E) {
    int i = blockIdx.x * 256 + threadIdx.x;
    if (i < E) {
        int d = dst[i];
        int pos = atomicAdd(&cursor[d], 1);
        elist[pos] = i;
    }
}

// ---------------------------------------------------------------------------
// Edge K/V projection via bf16 MFMA + attention scores. Edge-ordered outputs
// (fully coalesced, block-contiguous 16KB V runs — no partial-line RMW).
// ---------------------------------------------------------------------------
__global__ __launch_bounds__(256, 3) void k_edge(const float* __restrict__ h,
                                                 const float* __restrict__ f,
                                                 const float* __restrict__ dtv,
                                                 const int* __restrict__ src_idx,
                                                 const int* __restrict__ dst_idx,
                                                 const float* __restrict__ w_t,
                                                 const float* __restrict__ b_t,
                                                 const unsigned short* __restrict__ WS,
                                                 const float* __restrict__ bk,
                                                 const float* __restrict__ bv,
                                                 const float* __restrict__ qn,
                                                 unsigned short* __restrict__ Vout,
                                                 float* __restrict__ score,
                                                 int E) {
    __shared__ unsigned short At[64 * LDA];
    __shared__ int sidx[64];
    __shared__ int didx[64];

    const int tid = threadIdx.x;
    const int e0  = blockIdx.x * 64;

    if (tid < 64) {
        int ge = min(e0 + tid, E - 1);
        sidx[tid] = src_idx[ge];
        didx[tid] = dst_idx[ge];
    }
    __syncthreads();

    // ---- stage A: 16-deep batched loads (h|f), then time features ----
    {
        const int e  = tid >> 2;          // 0..63
        const int qb = tid & 3;
        const int ge = min(e0 + e, E - 1);
        const int s  = sidx[e];
        const float dte = dtv[ge];
        const float* hb = &h[(size_t)s * DN];
        const float* fb = &f[(size_t)ge * DE];
        float4 buf[16];

        #pragma unroll
        for (int it = 0; it < 8; ++it) buf[it]     = *(const float4*)&hb[qb * 4 + it * 16];
        #pragma unroll
        for (int it = 0; it < 8; ++it) buf[8 + it] = *(const float4*)&fb[qb * 4 + it * 16];
        #pragma unroll
        for (int it = 0; it < 16; ++it) {
            int c = (it < 8) ? (qb * 4 + it * 16) : (128 + qb * 4 + (it - 8) * 16);
            union { unsigned short us[4]; uint2 u2; } pk;
            pk.us[0] = f2bf(buf[it].x); pk.us[1] = f2bf(buf[it].y);
            pk.us[2] = f2bf(buf[it].z); pk.us[3] = f2bf(buf[it].w);
            *(uint2*)&At[e * LDA + c] = pk.u2;
        }
        #pragma unroll
        for (int it = 0; it < 8; ++it) {
            int t0 = qb * 4 + it * 16;         // 0..124, multiple of 4
            float4 v = make_float4(0.f, 0.f, 0.f, 0.f);
            if (t0 < DTF) {
                v.x = fastcos(dte * w_t[t0 + 0] + b_t[t0 + 0]);
                v.y = fastcos(dte * w_t[t0 + 1] + b_t[t0 + 1]);
                v.z = fastcos(dte * w_t[t0 + 2] + b_t[t0 + 2]);
                v.w = fastcos(dte * w_t[t0 + 3] + b_t[t0 + 3]);
            }
            union { unsigned short us[4]; uint2 u2; } pk;
            pk.us[0] = f2bf(v.x); pk.us[1] = f2bf(v.y);
            pk.us[2] = f2bf(v.z); pk.us[3] = f2bf(v.w);
            *(uint2*)&At[e * LDA + 256 + t0] = pk.u2;
        }
    }
    __syncthreads();

    // ---- MFMA main loop, A/B register double-buffered ----
    const int lane = tid & 63;
    const int w    = tid >> 6;
    const int t16  = lane & 15;
    const int qd   = lane >> 4;
    const int w4   = w * 4;

    f32x4 acc[4][4];
    #pragma unroll
    for (int r = 0; r < 4; ++r)
        #pragma unroll
        for (int c = 0; c < 4; ++c)
            acc[r][c] = (f32x4){0.f, 0.f, 0.f, 0.f};

    short8 aC[4], aN[4], bC[4], bN[4];
    #pragma unroll
    for (int r = 0; r < 4; ++r)
        aC[r] = *(const short8*)&At[(r * 16 + t16) * LDA + qd * 8];
    #pragma unroll
    for (int c = 0; c < 4; ++c)
        bC[c] = *(const short8*)(WS + (size_t)((w4 + c) * 64 + lane) * 8);

    #pragma unroll 1
    for (int kc = 0; kc < 12; kc += 2) {
        #pragma unroll
        for (int r = 0; r < 4; ++r)
            aN[r] = *(const short8*)&At[(r * 16 + t16) * LDA + (kc + 1) * 32 + qd * 8];
        #pragma unroll
        for (int c = 0; c < 4; ++c)
            bN[c] = *(const short8*)(WS + (size_t)(((kc + 1) * 16 + w4 + c) * 64 + lane) * 8);
        #pragma unroll
        for (int r = 0; r < 4; ++r)
            #pragma unroll
            for (int c = 0; c < 4; ++c)
                acc[r][c] = __builtin_amdgcn_mfma_f32_16x16x32_bf16(aC[r], bC[c], acc[r][c], 0, 0, 0);
        if (kc + 2 < 12) {
            #pragma unroll
            for (int r = 0; r < 4; ++r)
                aC[r] = *(const short8*)&At[(r * 16 + t16) * LDA + (kc + 2) * 32 + qd * 8];
            #pragma unroll
            for (int c = 0; c < 4; ++c)
                bC[c] = *(const short8*)(WS + (size_t)(((kc + 2) * 16 + w4 + c) * 64 + lane) * 8);
        }
        #pragma unroll
        for (int r = 0; r < 4; ++r)
            #pragma unroll
            for (int c = 0; c < 4; ++c)
                acc[r][c] = __builtin_amdgcn_mfma_f32_16x16x32_bf16(aN[r], bN[c], acc[r][c], 0, 0, 0);
    }

    // ---- epilogue (C/D: outcol = c*16+t16, edge = r*16 + qd*4 + i) ----
    if (w >= 2) {
        const int vc0 = (w - 2) * 64;
        float bvv[4];
        #pragma unroll
        for (int c = 0; c < 4; ++c) bvv[c] = bv[vc0 + c * 16 + t16];
        #pragma unroll
        for (int r = 0; r < 4; ++r) {
            #pragma unroll
            for (int i = 0; i < 4; ++i) {
                int el = r * 16 + qd * 4 + i;
                int ge = e0 + el;
                if (ge < E) {
                    unsigned short* vr = &Vout[(size_t)ge * DOUT + vc0 + t16];
                    #pragma unroll
                    for (int c = 0; c < 4; ++c)
                        vr[c * 16] = f2bf(acc[r][c][i] + bvv[c]);
                }
            }
        }
    } else {
        float bkc[4];
        #pragma unroll
        for (int c = 0; c < 4; ++c)
            bkc[c] = bk[w * 64 + c * 16 + t16];
        #pragma unroll
        for (int r = 0; r < 4; ++r) {
            #pragma unroll
            for (int i = 0; i < 4; ++i) {
                const int el = r * 16 + qd * 4 + i;
                const int d  = didx[el];
                const float* qrow = &qn[(size_t)d * DOUT + w * 64 + t16];
                float p = (acc[r][0][i] + bkc[0]) * qrow[0]
                        + (acc[r][1][i] + bkc[1]) * qrow[16]
                        + (acc[r][2][i] + bkc[2]) * qrow[32]
                        + (acc[r][3][i] + bkc[3]) * qrow[48];
                p += __shfl_xor(p, 1);
                p += __shfl_xor(p, 2);
                p += __shfl_xor(p, 4);
                p += __shfl_xor(p, 8);
                if (t16 == 0) {
                    int ge = e0 + el;
                    if (ge < E) {
                        float sc = (p >= 0.f) ? p : LEAKY * p;
                        score[(size_t)ge * 2 + w] = sc;
                    }
                }
            }
        }
    }
}

// ---------------------------------------------------------------------------
// Per-dst: softmax + weighted V sum (gather via elist) + out-proj + ReLU + LN.
// 512 threads = 16 dsts x 32 threads (4 cols each). WoutT staged via LDS.
// ---------------------------------------------------------------------------
__global__ __launch_bounds__(512) void k_dst(const unsigned short* __restrict__ V,
                                             const float* __restrict__ score,
                                             const int* __restrict__ offs,
                                             const int* __restrict__ elist,
                                             const float* __restrict__ h,
                                             const float* __restrict__ WT,
                                             const float* __restrict__ bout,
                                             const float* __restrict__ ln_w,
                                             const float* __restrict__ ln_b,
                                             float* __restrict__ out) {
    const int tid = threadIdx.x;
    const int s   = tid >> 5;        // sub 0..15
    const int t32 = tid & 31;
    const int d   = blockIdx.x * 16 + s;
    const bool valid = d < N_DST;
    const int beg = valid ? offs[d] : 0;
    const int end = valid ? offs[d + 1] : 0;

    __shared__ float inc[16][256];
    __shared__ float wchunk[64 * 128];

    // pass A: per-head max
    float m0 = -1e30f, m1 = -1e30f;
    for (int i = beg + t32; i < end; i += 32) {
        int e = elist[i];
        float2 sc = *(const float2*)&score[(size_t)e * 2];
        m0 = fmaxf(m0, sc.x);
        m1 = fmaxf(m1, sc.y);
    }
    #pragma unroll
    for (int o = 1; o < 32; o <<= 1) {
        m0 = fmaxf(m0, __shfl_xor(m0, o));
        m1 = fmaxf(m1, __shfl_xor(m1, o));
    }
    const int   hd = t32 >> 4;
    const float mh = hd ? m1 : m0;

    // pass B: exp-weighted V accumulation (V rows gathered, 256B granules)
    float a0 = 0.f, a1 = 0.f, a2 = 0.f, a3 = 0.f, l = 0.f;
    int i = beg;
    for (; i + 1 < end; i += 2) {
        int ea = elist[i], eb = elist[i + 1];
        float s0 = score[(size_t)ea * 2 + hd];
        float s1 = score[(size_t)eb * 2 + hd];
        ushort4 v0 = *(const ushort4*)&V[(size_t)ea * DOUT + t32 * 4];
        ushort4 v1 = *(const ushort4*)&V[(size_t)eb * DOUT + t32 * 4];
        float w0 = __expf(s0 - mh);
        float w1 = __expf(s1 - mh);
        l += w0 + w1;
        a0 += w0 * bf2f(v0.x) + w1 * bf2f(v1.x);
        a1 += w0 * bf2f(v0.y) + w1 * bf2f(v1.y);
        a2 += w0 * bf2f(v0.z) + w1 * bf2f(v1.z);
        a3 += w0 * bf2f(v0.w) + w1 * bf2f(v1.w);
    }
    if (i < end) {
        int ea = elist[i];
        float s0 = score[(size_t)ea * 2 + hd];
        ushort4 v0 = *(const ushort4*)&V[(size_t)ea * DOUT + t32 * 4];
        float w0 = __expf(s0 - mh);
        l += w0;
        a0 += w0 * bf2f(v0.x);
        a1 += w0 * bf2f(v0.y);
        a2 += w0 * bf2f(v0.z);
        a3 += w0 * bf2f(v0.w);
    }
    float inv = (l > 0.f) ? (1.f / l) : 0.f;
    inc[s][t32 * 4 + 0] = a0 * inv;
    inc[s][t32 * 4 + 1] = a1 * inv;
    inc[s][t32 * 4 + 2] = a2 * inv;
    inc[s][t32 * 4 + 3] = a3 * inv;
    {
        float4 hh = make_float4(0.f, 0.f, 0.f, 0.f);
        if (valid) hh = *(const float4*)&h[(size_t)d * DN + t32 * 4];
        *(float4*)&inc[s][128 + t32 * 4] = hh;
    }

    // out-proj: r4 = bout + WoutT . inc, staged in 4 x 32KB LDS chunks
    float4 r4 = *(const float4*)&bout[t32 * 4];
    #pragma unroll 1
    for (int ch = 0; ch < 4; ++ch) {
        __syncthreads();
        for (int u = tid; u < 2048; u += 512)
            *(float4*)&wchunk[u * 4] = *(const float4*)&WT[(size_t)ch * 8192 + u * 4];
        __syncthreads();
        #pragma unroll 4
        for (int kk = 0; kk < 64; ++kk) {
            float ic = inc[s][ch * 64 + kk];
            float4 w4 = *(float4*)&wchunk[kk * 128 + t32 * 4];
            r4.x += w4.x * ic;
            r4.y += w4.y * ic;
            r4.z += w4.z * ic;
            r4.w += w4.w * ic;
        }
    }
    r4.x = fmaxf(r4.x, 0.f);
    r4.y = fmaxf(r4.y, 0.f);
    r4.z = fmaxf(r4.z, 0.f);
    r4.w = fmaxf(r4.w, 0.f);

    // LayerNorm over the dst's 128 cols (32 lanes x 4)
    float s1 = r4.x + r4.y + r4.z + r4.w;
    float s2 = r4.x * r4.x + r4.y * r4.y + r4.z * r4.z + r4.w * r4.w;
    #pragma unroll
    for (int o = 1; o < 32; o <<= 1) {
        s1 += __shfl_xor(s1, o);
        s2 += __shfl_xor(s2, o);
    }
    float mu  = s1 * (1.f / 128.f);
    float var = s2 * (1.f / 128.f) - mu * mu;
    float rsd = rsqrtf(var + LN_EPS);
    if (valid) {
        float4 lw = *(const float4*)&ln_w[t32 * 4];
        float4 lb = *(const float4*)&ln_b[t32 * 4];
        float4 o4;
        o4.x = (r4.x - mu) * rsd * lw.x + lb.x;
        o4.y = (r4.y - mu) * rsd * lw.y + lb.y;
        o4.z = (r4.z - mu) * rsd * lw.z + lb.z;
        o4.w = (r4.w - mu) * rsd * lw.w + lb.w;
        *(float4*)&out[(size_t)d * DOUT + t32 * 4] = o4;
    }
}

// ---------------------------------------------------------------------------
extern "C" void kernel_launch(void* const* d_in, const int* in_sizes, int n_in,
                              void* d_out, int out_size, void* d_ws, size_t ws_size,
                              hipStream_t stream) {
    const float* h       = (const float*)d_in[0];
    const float* f       = (const float*)d_in[1];
    const float* dt      = (const float*)d_in[2];
    const int*   src_idx = (const int*)d_in[3];
    const int*   dst_idx = (const int*)d_in[4];
    const float* w_t     = (const float*)d_in[5];
    const float* b_t     = (const float*)d_in[6];
    const float* Wq      = (const float*)d_in[7];
    const float* bq      = (const float*)d_in[8];
    const float* Wk      = (const float*)d_in[9];
    const float* bk      = (const float*)d_in[10];
    const float* Wv      = (const float*)d_in[11];
    const float* bv      = (const float*)d_in[12];
    const float* Wout    = (const float*)d_in[13];
    const float* bout    = (const float*)d_in[14];
    const float* ln_w    = (const float*)d_in[15];
    const float* ln_b    = (const float*)d_in[16];
    float*       out     = (float*)d_out;

    const int E = in_sizes[2];

    char* ws = (char*)d_ws;
    unsigned short* V  = (unsigned short*)(ws + OFF_V);
    float* score       = (float*)(ws + OFF_SCORE);
    float* qn          = (float*)(ws + OFF_QN);
    unsigned short* WS = (unsigned short*)(ws + OFF_WS);
    float* WT          = (float*)(ws + OFF_WT);
    int*   cnt         = (int*)(ws + OFF_CNT);
    int*   offs        = (int*)(ws + OFF_OFFS);
    int*   cursor      = (int*)(ws + OFF_CURSOR);
    int*   elist       = (int*)(ws + OFF_ELIST);

    hipMemsetAsync(cnt, 0, N_DST * sizeof(int), stream);

    k_prepw<<<256, 128, 0, stream>>>(Wk, Wv, WS);
    k_prepwt<<<256, 128, 0, stream>>>(Wout, WT);
    k_qnodes<<<(N_DST + 15) / 16, 256, 0, stream>>>(h, Wq, bq, b_t, qn);
    k_hist<<<(E + 255) / 256, 256, 0, stream>>>(dst_idx, cnt, E);
    k_scan<<<1, 256, 0, stream>>>(cnt, offs, cursor);
    k_scatter<<<(E + 255) / 256, 256, 0, stream>>>(dst_idx, cursor, elist, E);
    k_edge<<<(E + 63) / 64, 256, 0, stream>>>(h, f, dt, src_idx, dst_idx,
                                              w_t, b_t, WS, bk, bv, qn, V, score, E);
    k_dst<<<(N_DST + 15) / 16, 512, 0, stream>>>(V, score, offs, elist, h, WT, bout,
                                                 ln_w, ln_b, out);
}